// Round 3
// baseline (443.079 us; speedup 1.0000x reference)
//
#include <hip/hip_runtime.h>

#define BS 8
#define LQ 900
#define NH 8
#define NL 4
#define NP 4
#define HD 32
#define ED 256
#define LEN_V 21760

typedef __attribute__((ext_vector_type(8))) short bf16x8;
typedef __attribute__((ext_vector_type(4))) float f32x4;
typedef __attribute__((ext_vector_type(4))) float fv4;

static __device__ __forceinline__ unsigned short f2bf(float f) {
  union { float f; unsigned u; } x; x.f = f;
  unsigned r = x.u + 0x7fffu + ((x.u >> 16) & 1u);
  return (unsigned short)(r >> 16);
}
static __device__ __forceinline__ float bf2f(unsigned short s) {
  union { unsigned u; float f; } x; x.u = ((unsigned)s) << 16;
  return x.f;
}
static __device__ __forceinline__ unsigned pack2(float a, float b) {
  return (unsigned)f2bf(a) | ((unsigned)f2bf(b) << 16);
}

// ---------------------------------------------------------------------------
// K1: v = value @ w_value + b_value  (bf16 MFMA), output permuted [b][h][s][d]
// bf16. (unchanged from round 2)
// ---------------------------------------------------------------------------
__global__ __launch_bounds__(256, 3) void vproj_kernel(
    const float* __restrict__ value, const float* __restrict__ w,
    const float* __restrict__ bias, unsigned short* __restrict__ vout) {
  const int t = threadIdx.x;
  const int row0 = blockIdx.x * 64;
  const int wv = t >> 6;
  const int lane = t & 63;
  const int quad = lane >> 4;
  const int nn = lane & 15;

  __shared__ unsigned short a_lds[4 * 64 * 8];
  __shared__ unsigned short b_lds[4 * 256 * 8];

  f32x4 acc[4][4];
#pragma unroll
  for (int i = 0; i < 4; i++)
#pragma unroll
    for (int j = 0; j < 4; j++) acc[i][j] = (f32x4)(0.f);

  const int arow = t >> 2;
  const int akseg = t & 3;
  const int bkseg = wv;
  const int bn = lane;

  for (int k0 = 0; k0 < 256; k0 += 32) {
    __syncthreads();
    {
      const float* pa = &value[(row0 + arow) * 256 + k0 + akseg * 8];
      fv4 v0 = __builtin_nontemporal_load((const fv4*)pa);
      fv4 v1 = __builtin_nontemporal_load((const fv4*)(pa + 4));
      uint4 pk;
      pk.x = pack2(v0.x, v0.y);
      pk.y = pack2(v0.z, v0.w);
      pk.z = pack2(v1.x, v1.y);
      pk.w = pack2(v1.z, v1.w);
      *(uint4*)&a_lds[(akseg * 64 + arow) * 8] = pk;
    }
    {
      const float* pb = &w[(k0 + bkseg * 8) * 256 + bn];
#pragma unroll
      for (int c = 0; c < 4; c++) {
        float f[8];
#pragma unroll
        for (int j = 0; j < 8; j++) f[j] = pb[j * 256 + c * 64];
        uint4 pk;
        pk.x = pack2(f[0], f[1]);
        pk.y = pack2(f[2], f[3]);
        pk.z = pack2(f[4], f[5]);
        pk.w = pack2(f[6], f[7]);
        *(uint4*)&b_lds[(bkseg * 256 + c * 64 + bn) * 8] = pk;
      }
    }
    __syncthreads();

    bf16x8 af[4], bf[4];
#pragma unroll
    for (int rt = 0; rt < 4; rt++)
      af[rt] = *(const bf16x8*)&a_lds[(quad * 64 + rt * 16 + nn) * 8];
#pragma unroll
    for (int ct = 0; ct < 4; ct++)
      bf[ct] = *(const bf16x8*)&b_lds[(quad * 256 + wv * 64 + ct * 16 + nn) * 8];
#pragma unroll
    for (int rt = 0; rt < 4; rt++)
#pragma unroll
      for (int ct = 0; ct < 4; ct++)
        acc[rt][ct] = __builtin_amdgcn_mfma_f32_16x16x32_bf16(
            af[rt], bf[ct], acc[rt][ct], 0, 0, 0);
  }

#pragma unroll
  for (int ct = 0; ct < 4; ct++) {
    const int col = wv * 64 + ct * 16 + nn;
    const float bv = bias[col];
    const int h = col >> 5;
    const int d = col & 31;
#pragma unroll
    for (int rt = 0; rt < 4; rt++) {
      f32x4 f = acc[rt][ct];
#pragma unroll
      for (int reg = 0; reg < 4; reg++) {
        const int grow = row0 + rt * 16 + quad * 4 + reg;
        const int b = grow / LEN_V;
        const int s = grow - b * LEN_V;
        vout[((b * NH + h) * LEN_V + s) * HD + d] = f2bf(f[reg] + bv);
      }
    }
  }
}

// ---------------------------------------------------------------------------
// K2: OFF = query@w_off + b_off (N=256) and LOG = query@w_attn + b_attn
// (N=128), fused as N=384. 384 threads, 32 rows/block, fp32.
// ---------------------------------------------------------------------------
__global__ __launch_bounds__(384, 2) void offattn_kernel(
    const float* __restrict__ query,
    const float* __restrict__ w_off, const float* __restrict__ b_off,
    const float* __restrict__ w_attn, const float* __restrict__ b_attn,
    float* __restrict__ OFF, float* __restrict__ LOG) {
  const int t = threadIdx.x;
  const int row0 = blockIdx.x * 32;
  const int rg = t / 96;          // 0..3 -> rows rg*8..+8
  const int c4 = t % 96;
  const int col = c4 * 4;         // 0..380
  const bool isOff = col < 256;
  const float* wbase = isOff ? (w_off + col) : (w_attn + (col - 256));
  const int wstride = isOff ? 256 : 128;
  const float* bb = isOff ? (b_off + col) : (b_attn + (col - 256));
  __shared__ float a_lds[32][8];

  float4 acc[8];
#pragma unroll
  for (int r = 0; r < 8; r++) acc[r] = make_float4(0.f, 0.f, 0.f, 0.f);

  for (int k0 = 0; k0 < 256; k0 += 8) {
    __syncthreads();
    if (t < 256) a_lds[t >> 3][t & 7] = query[(row0 + (t >> 3)) * 256 + k0 + (t & 7)];
    __syncthreads();
    float4 wr[8];
#pragma unroll
    for (int k = 0; k < 8; k++)
      wr[k] = *(const float4*)&wbase[(k0 + k) * wstride];
#pragma unroll
    for (int r = 0; r < 8; r++) {
      const float* ar = &a_lds[rg * 8 + r][0];
      float4 a0 = *(const float4*)&ar[0];
      float4 a1 = *(const float4*)&ar[4];
      float4 s = acc[r];
      s.x += a0.x*wr[0].x + a0.y*wr[1].x + a0.z*wr[2].x + a0.w*wr[3].x
           + a1.x*wr[4].x + a1.y*wr[5].x + a1.z*wr[6].x + a1.w*wr[7].x;
      s.y += a0.x*wr[0].y + a0.y*wr[1].y + a0.z*wr[2].y + a0.w*wr[3].y
           + a1.x*wr[4].y + a1.y*wr[5].y + a1.z*wr[6].y + a1.w*wr[7].y;
      s.z += a0.x*wr[0].z + a0.y*wr[1].z + a0.z*wr[2].z + a0.w*wr[3].z
           + a1.x*wr[4].z + a1.y*wr[5].z + a1.z*wr[6].z + a1.w*wr[7].z;
      s.w += a0.x*wr[0].w + a0.y*wr[1].w + a0.z*wr[2].w + a0.w*wr[3].w
           + a1.x*wr[4].w + a1.y*wr[5].w + a1.z*wr[6].w + a1.w*wr[7].w;
      acc[r] = s;
    }
  }

  const float4 bv = *(const float4*)bb;
#pragma unroll
  for (int r = 0; r < 8; r++) {
    const int grow = row0 + rg * 8 + r;
    float4 o = make_float4(acc[r].x + bv.x, acc[r].y + bv.y,
                           acc[r].z + bv.z, acc[r].w + bv.w);
    if (isOff) *(float4*)&OFF[grow * 256 + col] = o;
    else       *(float4*)&LOG[grow * 128 + (col - 256)] = o;
  }
}

// ---------------------------------------------------------------------------
// K3: softmax + bilinear sampling. One block per (b, 4 queries), 256 threads.
// Phase B: 512 (qi,h,l,p) sets -> corner addrs + aw-folded weights in LDS.
// Phase C: thread=(q-pair, head, dim-pair): 4 uint gathers (2 bf16) per set.
// ---------------------------------------------------------------------------
__global__ __launch_bounds__(256, 4) void sample_kernel(
    const float* __restrict__ refp, const unsigned short* __restrict__ vp,
    const float* __restrict__ OFF, const float* __restrict__ LOG,
    float* __restrict__ RES) {
  const int t = threadIdx.x;
  const int b = blockIdx.x / (LQ / 4);
  const int q0 = (blockIdx.x % (LQ / 4)) * 4;

  __shared__ float off_lds[4][256];
  __shared__ float aw_lds[4][128];
  __shared__ float ref_lds[4][4][2];
  __shared__ int   soff[512][4];   // uint-offsets of 4 corners
  __shared__ float swt[512][4];    // aw-folded corner weights

  // ---- phase A: load projections + refs ----
#pragma unroll
  for (int qi = 0; qi < 4; qi++)
    off_lds[qi][t] = OFF[(b * LQ + q0 + qi) * 256 + t];
  if (t < 128) {
#pragma unroll
    for (int qi = 0; qi < 4; qi++)
      aw_lds[qi][t] = LOG[(b * LQ + q0 + qi) * 128 + t];
  }
  if (t < 32) {
    const int qi = t >> 3, l = (t >> 1) & 3, xy = t & 1;
    ref_lds[qi][l][xy] = refp[((b * LQ + q0 + qi) * NL + l) * 2 + xy];
  }
  __syncthreads();

  // ---- softmax over 16 (l,p) per (qi,h) ----
  if (t < 32) {
    const int qi = t >> 3, h = t & 7;
    float* a = &aw_lds[qi][h * 16];
    float m = a[0];
#pragma unroll
    for (int i = 1; i < 16; i++) m = fmaxf(m, a[i]);
    float e[16];
    float ssum = 0.f;
#pragma unroll
    for (int i = 0; i < 16; i++) { e[i] = __expf(a[i] - m); ssum += e[i]; }
    const float inv = 1.f / ssum;
#pragma unroll
    for (int i = 0; i < 16; i++) a[i] = e[i] * inv;
  }
  __syncthreads();

  // ---- phase B: corner addresses + weights, 2 sets per thread ----
#pragma unroll
  for (int ss = 0; ss < 2; ss++) {
    const int sid = t + ss * 256;
    const int p = sid & 3, l = (sid >> 2) & 3, h = (sid >> 4) & 7, qi = sid >> 7;
    const int W = 128 >> l;
    const int base = (l == 0) ? 0 : ((l == 1) ? 16384 : ((l == 2) ? 20480 : 21504));
    const float Wf = (float)W;
    const float refx = ref_lds[qi][l][0];
    const float refy = ref_lds[qi][l][1];
    const float offx = off_lds[qi][h * 32 + l * 8 + p * 2 + 0];
    const float offy = off_lds[qi][h * 32 + l * 8 + p * 2 + 1];
    const float aw = aw_lds[qi][h * 16 + l * 4 + p];
    const float px = refx * Wf + offx - 0.5f;
    const float py = refy * Wf + offy - 0.5f;
    const float x0f = floorf(px), y0f = floorf(py);
    const float dx = px - x0f, dy = py - y0f;
    const int x0 = (int)x0f, y0 = (int)y0f;
    const int x1 = x0 + 1, y1 = y0 + 1;
    const float mx0 = (x0 >= 0 && x0 < W) ? 1.f : 0.f;
    const float mx1 = (x1 >= 0 && x1 < W) ? 1.f : 0.f;
    const float my0 = (y0 >= 0 && y0 < W) ? 1.f : 0.f;
    const float my1 = (y1 >= 0 && y1 < W) ? 1.f : 0.f;
    const int x0c = min(max(x0, 0), W - 1);
    const int x1c = min(max(x1, 0), W - 1);
    const int y0c = min(max(y0, 0), W - 1);
    const int y1c = min(max(y1, 0), W - 1);
    soff[sid][0] = (base + y0c * W + x0c) * 16;  // uint units (32 bf16 = 16 uints)
    soff[sid][1] = (base + y0c * W + x1c) * 16;
    soff[sid][2] = (base + y1c * W + x0c) * 16;
    soff[sid][3] = (base + y1c * W + x1c) * 16;
    swt[sid][0] = (1.f - dx) * (1.f - dy) * mx0 * my0 * aw;
    swt[sid][1] = dx * (1.f - dy) * mx1 * my0 * aw;
    swt[sid][2] = (1.f - dx) * dy * mx0 * my1 * aw;
    swt[sid][3] = dx * dy * mx1 * my1 * aw;
  }
  __syncthreads();

  // ---- phase C: gather + accumulate. thread -> (qsel, head, dim-pair) ----
  const int qsel = t >> 7;        // 0/1
  const int hh = (t >> 4) & 7;
  const int d2 = t & 15;          // dim pair
  const unsigned* vpu = (const unsigned*)vp + (size_t)(b * NH + hh) * (LEN_V * HD / 2);
#pragma unroll
  for (int j = 0; j < 2; j++) {
    const int qi = qsel * 2 + j;
    float r0 = 0.f, r1 = 0.f;
#pragma unroll
    for (int lp = 0; lp < 16; lp++) {
      const int sid = ((qi * 8 + hh) << 4) + lp;
      const int4 o = *(const int4*)&soff[sid][0];
      const float4 w = *(const float4*)&swt[sid][0];
      const unsigned u00 = vpu[o.x + d2];
      const unsigned u10 = vpu[o.y + d2];
      const unsigned u01 = vpu[o.z + d2];
      const unsigned u11 = vpu[o.w + d2];
      r0 += w.x * bf2f((unsigned short)(u00 & 0xffff))
          + w.y * bf2f((unsigned short)(u10 & 0xffff))
          + w.z * bf2f((unsigned short)(u01 & 0xffff))
          + w.w * bf2f((unsigned short)(u11 & 0xffff));
      r1 += w.x * bf2f((unsigned short)(u00 >> 16))
          + w.y * bf2f((unsigned short)(u10 >> 16))
          + w.z * bf2f((unsigned short)(u01 >> 16))
          + w.w * bf2f((unsigned short)(u11 >> 16));
    }
    float2 rr = make_float2(r0, r1);
    *(float2*)&RES[(b * LQ + q0 + qi) * 256 + hh * 32 + d2 * 2] = rr;
  }
}

// ---------------------------------------------------------------------------
// K4: out = RES @ w_out + b_out. fp32 register-tiled, 32 rows/block.
// ---------------------------------------------------------------------------
__global__ __launch_bounds__(256, 2) void outproj_kernel(
    const float* __restrict__ RES, const float* __restrict__ w,
    const float* __restrict__ bias, float* __restrict__ out) {
  const int t = threadIdx.x;
  const int row0 = blockIdx.x * 32;
  const int rg = t >> 6;
  const int c0 = (t & 63) << 2;
  __shared__ float a_lds[32][8];

  float4 acc[8];
#pragma unroll
  for (int r = 0; r < 8; r++) acc[r] = make_float4(0.f, 0.f, 0.f, 0.f);

  const int lr = t >> 3;
  const int lk = t & 7;
  for (int k0 = 0; k0 < 256; k0 += 8) {
    __syncthreads();
    a_lds[lr][lk] = RES[(row0 + lr) * 256 + k0 + lk];
    __syncthreads();
    float4 wr[8];
#pragma unroll
    for (int k = 0; k < 8; k++)
      wr[k] = *(const float4*)&w[(k0 + k) * 256 + c0];
#pragma unroll
    for (int r = 0; r < 8; r++) {
      const float* ar = &a_lds[rg * 8 + r][0];
      float4 a0 = *(const float4*)&ar[0];
      float4 a1 = *(const float4*)&ar[4];
      float4 s = acc[r];
      s.x += a0.x*wr[0].x + a0.y*wr[1].x + a0.z*wr[2].x + a0.w*wr[3].x
           + a1.x*wr[4].x + a1.y*wr[5].x + a1.z*wr[6].x + a1.w*wr[7].x;
      s.y += a0.x*wr[0].y + a0.y*wr[1].y + a0.z*wr[2].y + a0.w*wr[3].y
           + a1.x*wr[4].y + a1.y*wr[5].y + a1.z*wr[6].y + a1.w*wr[7].y;
      s.z += a0.x*wr[0].z + a0.y*wr[1].z + a0.z*wr[2].z + a0.w*wr[3].z
           + a1.x*wr[4].z + a1.y*wr[5].z + a1.z*wr[6].z + a1.w*wr[7].z;
      s.w += a0.x*wr[0].w + a0.y*wr[1].w + a0.z*wr[2].w + a0.w*wr[3].w
           + a1.x*wr[4].w + a1.y*wr[5].w + a1.z*wr[6].w + a1.w*wr[7].w;
      acc[r] = s;
    }
  }

  const float4 bv = *(const float4*)&bias[c0];
#pragma unroll
  for (int r = 0; r < 8; r++) {
    const int grow = row0 + rg * 8 + r;
    float4 o = make_float4(acc[r].x + bv.x, acc[r].y + bv.y,
                           acc[r].z + bv.z, acc[r].w + bv.w);
    *(float4*)&out[grow * 256 + c0] = o;
  }
}

extern "C" void kernel_launch(void* const* d_in, const int* in_sizes, int n_in,
                              void* d_out, int out_size, void* d_ws, size_t ws_size,
                              hipStream_t stream) {
  (void)in_sizes; (void)n_in; (void)out_size; (void)ws_size;
  const float* query   = (const float*)d_in[0];
  const float* refp    = (const float*)d_in[1];
  const float* value   = (const float*)d_in[2];
  const float* w_value = (const float*)d_in[3];
  const float* b_value = (const float*)d_in[4];
  const float* w_off   = (const float*)d_in[5];
  const float* b_off   = (const float*)d_in[6];
  const float* w_attn  = (const float*)d_in[7];
  const float* b_attn  = (const float*)d_in[8];
  const float* w_out   = (const float*)d_in[9];
  const float* b_out   = (const float*)d_in[10];
  float* out = (float*)d_out;

  char* ws = (char*)d_ws;
  unsigned short* vp = (unsigned short*)ws;               // 89,128,960 B
  float* OFF = (float*)(ws + 89128960);                   // 7,372,800 B
  float* LOG = (float*)(ws + 89128960 + 7372800);         // 3,686,400 B
  float* RES = (float*)(ws + 89128960 + 7372800 + 3686400); // 7,372,800 B

  vproj_kernel<<<(BS * LEN_V) / 64, 256, 0, stream>>>(value, w_value, b_value, vp);
  offattn_kernel<<<(BS * LQ) / 32, 384, 0, stream>>>(query, w_off, b_off,
                                                     w_attn, b_attn, OFF, LOG);
  sample_kernel<<<BS * (LQ / 4), 256, 0, stream>>>(refp, vp, OFF, LOG, RES);
  outproj_kernel<<<(BS * LQ) / 32, 256, 0, stream>>>(RES, w_out, b_out, out);
}